// Round 12
// baseline (2443.374 us; speedup 1.0000x reference)
//
#include <hip/hip_runtime.h>
#include <hip/hip_fp16.h>

#define NT    365
#define NGRID 1000
#define NXI   20
#define HID   256
#define GATES 1024
#define MROWS 365000          // NT*NGRID
#define MBLK  5704            // ceil(MROWS/64)
#define MPAD  (MBLK * 64)
#define NCL   63              // clusters (16 pts each, last ragged)
#define CPTS  16
#define HX_TOT ((size_t)NT * NCL * 1024)   // u64 slots, deep buffer (188MB)
#define HX_ZERO ((size_t)NCL * 1024)       // t=0 region: zeros (h_0 = 0)

typedef _Float16 half8 __attribute__((ext_vector_type(8)));
typedef float floatx4 __attribute__((ext_vector_type(4)));
typedef unsigned long long u64;

#define SENT 0xFFFFFFFFFFFFFFFFull   // 4x fp16 -NaN: unreachable (|h|<=1)

union hpack { u64 u[2]; half8 h; _Float16 e[8]; };

// Module-scope globals (d_ws too small). Fully rewritten/reset every launch.
__device__ _Float16 g_gx[(size_t)MPAD * GATES];   // gx, block-local column layout
__device__ _Float16 g_wif[64 * 8 * 512];          // W_ih B-frags (global n-tiles)
__device__ _Float16 g_whf[2 * 32 * 8 * 64 * 8];   // W_hh B-frags, split by rec block
// h exchange, A-FRAGMENT ORDER, plane-split: chunk[ks*64 + lane] (+512 for the
// 2nd u64 of the half8). Coalesced polls AND publishes (wave owns one ks
// slice). Sentinel protocol; deep t-indexed buffer (no reuse at any skew).
__device__ u64 g_hx[HX_TOT];

__device__ __forceinline__ float fsig(float x) {
  return __fdividef(1.f, 1.f + __expf(-x));
}
__device__ __forceinline__ float ftanh(float x) {
  return 1.f - __fdividef(2.f, __expf(2.f * x) + 1.f);
}

// ---- init: zero y, zero g_hx[t=0], sentinel-fill the rest -----------------
__global__ __launch_bounds__(256) void init_kernel(float* __restrict__ y) {
  const size_t i = (size_t)blockIdx.x * 256 + threadIdx.x;
  const size_t j = i * 2;
  if (j < HX_TOT)     g_hx[j]     = (j < HX_ZERO)     ? 0ull : SENT;
  if (j + 1 < HX_TOT) g_hx[j + 1] = (j + 1 < HX_ZERO) ? 0ull : SENT;
  if (i < MROWS) y[i] = 0.f;
}

// ---- pack weights into MFMA B-fragment layouts ----------------------------
// B-frag 16x16x32: lane holds B[n=tile*16+(lane&15)][k=ks*32+(lane>>4)*8+j]
__global__ __launch_bounds__(256) void pack_wf_kernel(
    const float* __restrict__ W_ih, const float* __restrict__ W_hh) {
  const int gid = blockIdx.x * 256 + threadIdx.x;   // 0..65535
  const float* src;
  _Float16* dst;
  int n, k0, lane;
  if (gid < 32768) {                 // W_ih -> g_wif, global n-tile layout
    const int tile = gid >> 9;
    const int ks   = (gid >> 6) & 7;
    lane = gid & 63;
    n  = tile * 16 + (lane & 15);
    k0 = ks * 32 + (lane >> 4) * 8;
    src = W_ih + n * HID + k0;
    dst = g_wif + ((size_t)(tile * 8 + ks) * 64 + lane) * 8;
  } else {                           // W_hh -> g_whf, [b][ltile][ks global]
    const int rem = gid - 32768;
    const int b2  = rem >> 14;       // owning rec block (dim half)
    const int lt  = (rem >> 9) & 31; // local tile = tau*8 + sub
    const int ks  = (rem >> 6) & 7;
    lane = rem & 63;
    const int nt = (lt >> 3) * 16 + b2 * 8 + (lt & 7);
    n  = nt * 16 + (lane & 15);
    k0 = ks * 32 + (lane >> 4) * 8;
    src = W_hh + n * HID + k0;
    dst = g_whf + ((size_t)((b2 * 32 + lt) * 8 + ks) * 64 + lane) * 8;
  }
  const float4 a = *(const float4*)(src);
  const float4 b = *(const float4*)(src + 4);
  half8 h;
  h[0] = (_Float16)a.x; h[1] = (_Float16)a.y; h[2] = (_Float16)a.z; h[3] = (_Float16)a.w;
  h[4] = (_Float16)b.x; h[5] = (_Float16)b.y; h[6] = (_Float16)b.z; h[7] = (_Float16)b.w;
  *(half8*)dst = h;
}

// ---- gx = relu(x@W_in.T+b_in) @ W_ih.T + (b_ih+b_hh), fused ---------------
// Output column layout per row: phi(g) = b*512 + tau*128 + (g&127).
__global__ __launch_bounds__(256, 2) void gx_kernel(
    const float* __restrict__ x, const float* __restrict__ W_in,
    const float* __restrict__ b_in, const float* __restrict__ b_ih,
    const float* __restrict__ b_hh) {
  __shared__ float s_x[64 * NXI];
  __shared__ _Float16 s_x0[64 * 264];
  __shared__ _Float16 s_out[64 * 264];

  const int tid  = threadIdx.x;
  const int lane = tid & 63;
  const int w    = tid >> 6;
  const int m0   = blockIdx.x * 64;

  #pragma unroll
  for (int i = 0; i < 5; ++i) {
    const int idx = i * 256 + tid;
    size_t g = (size_t)m0 * NXI + idx;
    const size_t gmax = (size_t)MROWS * NXI - 1;
    if (g > gmax) g = gmax;
    s_x[idx] = x[g];
  }
  float wv[NXI];
  #pragma unroll
  for (int k = 0; k < NXI; ++k) wv[k] = W_in[tid * NXI + k];
  const float bv = b_in[tid];
  __syncthreads();

  for (int r = 0; r < 64; ++r) {
    float acc = bv;
    #pragma unroll
    for (int qq = 0; qq < 5; ++qq) {
      const float4 xa = *(const float4*)&s_x[r * NXI + qq * 4];
      acc += xa.x * wv[qq * 4 + 0] + xa.y * wv[qq * 4 + 1] +
             xa.z * wv[qq * 4 + 2] + xa.w * wv[qq * 4 + 3];
    }
    s_x0[r * 264 + tid] = (_Float16)fmaxf(acc, 0.f);
  }
  __syncthreads();

  for (int ng = 0; ng < 4; ++ng) {    // 4 groups of 256 gates
    floatx4 acc[4][4];
    #pragma unroll
    for (int mi = 0; mi < 4; ++mi)
      #pragma unroll
      for (int ni = 0; ni < 4; ++ni) acc[mi][ni] = (floatx4){0.f, 0.f, 0.f, 0.f};

    #pragma unroll
    for (int ks = 0; ks < 8; ++ks) {
      half8 a[4], bfr[4];
      #pragma unroll
      for (int mi = 0; mi < 4; ++mi)
        a[mi] = *(const half8*)&s_x0[(mi * 16 + (lane & 15)) * 264 + ks * 32 + (lane >> 4) * 8];
      #pragma unroll
      for (int ni = 0; ni < 4; ++ni) {
        const int nt = ng * 16 + w * 4 + ni;
        bfr[ni] = *(const half8*)(g_wif + ((size_t)(nt * 8 + ks) * 64 + lane) * 8);
      }
      #pragma unroll
      for (int mi = 0; mi < 4; ++mi)
        #pragma unroll
        for (int ni = 0; ni < 4; ++ni)
          acc[mi][ni] = __builtin_amdgcn_mfma_f32_16x16x32_f16(a[mi], bfr[ni], acc[mi][ni], 0, 0, 0);
    }

    #pragma unroll
    for (int ni = 0; ni < 4; ++ni) {
      const int g = ng * 256 + (w * 4 + ni) * 16 + (lane & 15);
      const float bias = b_ih[g] + b_hh[g];
      const int colw = (w * 4 + ni) * 16 + (lane & 15);
      #pragma unroll
      for (int mi = 0; mi < 4; ++mi)
        #pragma unroll
        for (int r = 0; r < 4; ++r)
          s_out[(mi * 16 + (lane >> 4) * 4 + r) * 264 + colw] = (_Float16)(acc[mi][ni][r] + bias);
    }
    __syncthreads();

    #pragma unroll
    for (int i = 0; i < 8; ++i) {
      const int cid = i * 256 + tid;             // 2048 chunks of 8 halfs
      const int row = cid >> 5;
      const int c8  = (cid & 31) * 8;
      const half8 v = *(const half8*)&s_out[row * 264 + c8];
      const int phi = ((c8 >> 7) & 1) * 512 + ng * 128 + (c8 & 127);
      *(half8*)(g_gx + (size_t)(m0 + row) * GATES + phi) = v;
    }
    __syncthreads();
  }
}

// ---- recurrent: 63 clusters x 2 blocks; ZERO barriers in the time loop ----
// Wave w of block b owns ks slice kown=b*4+w (dims 32*kown..+32, all 4 gate
// types). Own slice never leaves registers (pubPrev: lane l publishes exactly
// the chunk it consumes as A-frag next step). The 7 other slices are polled
// from the LLC with ONE batched spin; polls for t+1 and gx(t+1) are issued at
// the END of step t (right after publish) so detection at t+1 costs only the
// store-visibility latency. Max wave skew is <=1 step; deep buffer -> safe.
// wf slots: s=0..6 -> global ks ko[s] (own skipped), s=7 -> own. All register
// indices compile-time; runtime w/b only in addresses (round-8 lesson).
__global__ __launch_bounds__(256, 1) void rec_kernel(
    const float* __restrict__ W_out, const float* __restrict__ b_out,
    float* __restrict__ y) {
  __shared__ float s_g[4 * 16 * 132];  // per-wave gate regions (pad 132)

  const int tid = threadIdx.x;
  const int l   = tid & 63;
  const int w   = tid >> 6;
  const int c   = blockIdx.x >> 1;     // cluster
  const int b   = blockIdx.x & 1;      // dim-half owner
  const int pt  = l & 15;
  const int jg  = l >> 4;

  const int kown = b * 4 + w;          // this wave's ks slice (runtime)
  int ko[7];                           // the other 7 ks, constant-indexed init
  #pragma unroll
  for (int s = 0; s < 7; ++s) ko[s] = s + (s >= kown ? 1 : 0);

  // one-time: W_hh tiles -> registers. tile i: lt=(i>>1)*8+2w+(i&1).
  half8 wf[8][8];
  #pragma unroll
  for (int i = 0; i < 8; ++i) {
    const int lt = (i >> 1) * 8 + 2 * w + (i & 1);
    #pragma unroll
    for (int s = 0; s < 7; ++s)
      wf[i][s] = *(const half8*)(g_whf +
          ((size_t)((b * 32 + lt) * 8 + ko[s]) * 64 + l) * 8);
    wf[i][7] = *(const half8*)(g_whf +
        ((size_t)((b * 32 + lt) * 8 + kown) * 64 + l) * 8);
  }

  float cs[8];
  float wo[8];
  #pragma unroll
  for (int j = 0; j < 8; ++j) {
    cs[j] = 0.f;
    wo[j] = W_out[b * 128 + 32 * w + jg * 8 + j];
  }
  const float bo_eff = (b == 0 && w == 0) ? b_out[0] : 0.f;
  const int n_pt  = c * CPTS + pt;
  const int rn_pt = (n_pt < NGRID) ? n_pt : (NGRID - 1);

  // pipeline state: own chunk (h_0=0), polls + gx for t=0
  hpack pubPrev;
  pubPrev.u[0] = 0ull; pubPrev.u[1] = 0ull;

  u64 pv[14];
  {
    const u64* hsrc = g_hx + (size_t)c * 1024;   // t=0 region (zeros)
    #pragma unroll
    for (int s = 0; s < 7; ++s) {
      pv[2 * s]     = __hip_atomic_load(hsrc +       ko[s] * 64 + l,
                                        __ATOMIC_RELAXED, __HIP_MEMORY_SCOPE_AGENT);
      pv[2 * s + 1] = __hip_atomic_load(hsrc + 512 + ko[s] * 64 + l,
                                        __ATOMIC_RELAXED, __HIP_MEMORY_SCOPE_AGENT);
    }
  }
  half8 gxr[4];
  {
    const _Float16* gsrc = g_gx + (size_t)rn_pt * GATES + b * 512 + 32 * w + jg * 8;
    #pragma unroll
    for (int off = 0; off < 4; ++off) gxr[off] = *(const half8*)(gsrc + off * 128);
  }

  for (int t = 0; t < NT; ++t) {
    const u64* hsrc = g_hx + ((size_t)t * NCL + c) * 1024;

    floatx4 acc[8];
    #pragma unroll
    for (int i = 0; i < 8; ++i) acc[i] = (floatx4){0.f, 0.f, 0.f, 0.f};

    // 1) own-slot MFMAs immediately (data in registers, no wait)
    #pragma unroll
    for (int i = 0; i < 8; ++i)
      acc[i] = __builtin_amdgcn_mfma_f32_16x16x32_f16(pubPrev.h, wf[i][7], acc[i], 0, 0, 0);

    // 2) batched spin on the 7 polled slices (loads issued last iteration)
    {
      bool pending = false;
      #pragma unroll
      for (int k = 0; k < 14; ++k) pending |= (pv[k] == SENT);
      int tries = 0;
      while (pending && ++tries < (1 << 17)) {
        #pragma unroll
        for (int s = 0; s < 7; ++s) {
          if (pv[2 * s] == SENT)
            pv[2 * s] = __hip_atomic_load(hsrc + ko[s] * 64 + l,
                                          __ATOMIC_RELAXED, __HIP_MEMORY_SCOPE_AGENT);
          if (pv[2 * s + 1] == SENT)
            pv[2 * s + 1] = __hip_atomic_load(hsrc + 512 + ko[s] * 64 + l,
                                              __ATOMIC_RELAXED, __HIP_MEMORY_SCOPE_AGENT);
        }
        pending = false;
        #pragma unroll
        for (int k = 0; k < 14; ++k) pending |= (pv[k] == SENT);
      }
    }

    // 3) polled-slot MFMAs
    #pragma unroll
    for (int s = 0; s < 7; ++s) {
      hpack af;
      af.u[0] = pv[2 * s];
      af.u[1] = pv[2 * s + 1];
      #pragma unroll
      for (int i = 0; i < 8; ++i)
        acc[i] = __builtin_amdgcn_mfma_f32_16x16x32_f16(af.h, wf[i][s], acc[i], 0, 0, 0);
    }

    // 4) scatter acc -> wave-private s_g region (lgkmcnt only, no barrier)
    #pragma unroll
    for (int i = 0; i < 8; ++i) {
      const int colw = (i >> 1) * 32 + (i & 1) * 16 + pt;
      #pragma unroll
      for (int r = 0; r < 4; ++r)
        s_g[w * 2112 + (jg * 4 + r) * 132 + colw] = acc[i][r];
    }

    // 5) cell update for this lane's 8 dims; then publish + next-step issues
    {
      const float* gp = &s_g[w * 2112 + pt * 132 + jg * 8];
      hpack pub;
      float yp = 0.f;
      #pragma unroll
      for (int j = 0; j < 8; ++j) {
        const float gi = gp[j]      + (float)gxr[0][j];
        const float gf = gp[32 + j] + (float)gxr[1][j];
        const float gg = gp[64 + j] + (float)gxr[2][j];
        const float go = gp[96 + j] + (float)gxr[3][j];
        const float i_ = fsig(gi);
        const float f_ = fsig(gf);
        const float g_ = ftanh(gg);
        const float o_ = fsig(go);
        cs[j] = f_ * cs[j] + i_ * g_;
        const float h = o_ * ftanh(cs[j]);
        pub.e[j] = (_Float16)h;
        yp += wo[j] * h;
      }

      // 6) publish own slice for t+1 (2 coalesced 512B stores)
      if (t < NT - 1) {
        u64* dst = g_hx + ((size_t)(t + 1) * NCL + c) * 1024 + kown * 64 + l;
        __hip_atomic_store(dst,       pub.u[0], __ATOMIC_RELAXED, __HIP_MEMORY_SCOPE_AGENT);
        __hip_atomic_store(dst + 512, pub.u[1], __ATOMIC_RELAXED, __HIP_MEMORY_SCOPE_AGENT);

        // 7) issue polls for t+1 NOW (detection next iter ~ store latency)
        const u64* hn = g_hx + ((size_t)(t + 1) * NCL + c) * 1024;
        #pragma unroll
        for (int s = 0; s < 7; ++s) {
          pv[2 * s]     = __hip_atomic_load(hn +       ko[s] * 64 + l,
                                            __ATOMIC_RELAXED, __HIP_MEMORY_SCOPE_AGENT);
          pv[2 * s + 1] = __hip_atomic_load(hn + 512 + ko[s] * 64 + l,
                                            __ATOMIC_RELAXED, __HIP_MEMORY_SCOPE_AGENT);
        }
      }
      pubPrev = pub;

      // 8) y partial: reduce over the 4 jg-lanes of this pt, fire-and-forget
      yp += __shfl_xor(yp, 16);
      yp += __shfl_xor(yp, 32);
      if (jg == 0 && n_pt < NGRID)
        atomicAdd(&y[(size_t)t * NGRID + n_pt], yp + bo_eff);

      // 9) gx prefetch for t+1 (HBM latency hidden behind next step)
      const int tn = (t + 1 < NT) ? (t + 1) : t;
      const _Float16* gsrc = g_gx + ((size_t)tn * NGRID + rn_pt) * GATES
                           + b * 512 + 32 * w + jg * 8;
      #pragma unroll
      for (int off = 0; off < 4; ++off) gxr[off] = *(const half8*)(gsrc + off * 128);
    }
    // NO __syncthreads: s_g is wave-private; cross-block sync is the sentinel
  }
}

extern "C" void kernel_launch(void* const* d_in, const int* in_sizes, int n_in,
                              void* d_out, int out_size, void* d_ws, size_t ws_size,
                              hipStream_t stream) {
  (void)in_sizes; (void)n_in; (void)out_size; (void)d_ws; (void)ws_size;
  const float* x     = (const float*)d_in[0];
  // d_in[1] = wt_ih (zeros in eval mode, unused)
  const float* W_in  = (const float*)d_in[2];
  const float* b_in  = (const float*)d_in[3];
  const float* W_ih  = (const float*)d_in[4];
  const float* W_hh  = (const float*)d_in[5];
  const float* b_ih  = (const float*)d_in[6];
  const float* b_hh  = (const float*)d_in[7];
  const float* W_out = (const float*)d_in[8];
  const float* b_out = (const float*)d_in[9];
  float* y           = (float*)d_out;

  const int init_blocks = (int)((HX_TOT / 2 + 255) / 256);
  hipLaunchKernelGGL(init_kernel, dim3(init_blocks), dim3(256), 0, stream, y);
  hipLaunchKernelGGL(pack_wf_kernel, dim3(256), dim3(256), 0, stream, W_ih, W_hh);
  hipLaunchKernelGGL(gx_kernel, dim3(MBLK), dim3(256), 0, stream,
                     x, W_in, b_in, b_ih, b_hh);
  hipLaunchKernelGGL(rec_kernel, dim3(NCL * 2), dim3(256), 0, stream, W_out, b_out, y);
}